// Round 1
// baseline (235.460 us; speedup 1.0000x reference)
//
#include <hip/hip_runtime.h>

#define BATCH   4096
#define IN_DIM  1024
#define OUT_DIM 1024
#define NB      8                 // DEGREE + 1
#define KD      (IN_DIM * NB)     // 8192

typedef __bf16 bf16x8 __attribute__((ext_vector_type(8)));
typedef float  f32x4  __attribute__((ext_vector_type(4)));
typedef unsigned short us8 __attribute__((ext_vector_type(8)));

__device__ __forceinline__ unsigned short f2bf(float f) {
    unsigned int u = __float_as_uint(f);
    u += 0x7fffu + ((u >> 16) & 1u);   // round-to-nearest-even
    return (unsigned short)(u >> 16);
}

__device__ __forceinline__ void ld_lds16(const unsigned short* g, unsigned short* l) {
    __builtin_amdgcn_global_load_lds(
        (const __attribute__((address_space(1))) void*)g,
        (__attribute__((address_space(3))) void*)l, 16, 0, 0);
}

// ---------------------------------------------------------------------------
// Kernel 1: basis prep. A[b*KD + i*8 + d] = bf16(P_d(tanh(x[b,i])))
// ---------------------------------------------------------------------------
__global__ __launch_bounds__(256) void prep_basis(
    const float* __restrict__ x, const float* __restrict__ ap,
    const float* __restrict__ qp, unsigned short* __restrict__ Aw) {
    int idx = blockIdx.x * 256 + threadIdx.x;   // (b, i) flat, exact grid
    float a = ap[0], q = qp[0];
    float xt = tanhf(x[idx]);
    float p[NB];
    p[0] = 1.0f;
    p[1] = xt - a;
    float qn = q, qn1 = 1.0f;   // q^n, q^(n-1)
#pragma unroll
    for (int n = 2; n < NB; ++n) {
        qn *= q; qn1 *= q;
        p[n] = (xt - (a + qn)) * p[n - 1] - a * qn1 * p[n - 2];
    }
    us8 v;
#pragma unroll
    for (int d = 0; d < NB; ++d) v[d] = f2bf(p[d]);
    *(us8*)(Aw + (size_t)idx * NB) = v;   // 16B coalesced store
}

// ---------------------------------------------------------------------------
// Kernel 2: coeffs [I][O][8] fp32 -> Bt [O][KD] bf16, Bt[o][i*8+d]=coeffs[i][o][d]
// ---------------------------------------------------------------------------
__global__ __launch_bounds__(256) void repack_coeffs(
    const float* __restrict__ coeffs, unsigned short* __restrict__ Bt) {
    int idx = blockIdx.x * 256 + threadIdx.x;   // o major, i minor -> coalesced writes
    int o = idx >> 10;            // / IN_DIM
    int i = idx & (IN_DIM - 1);
    const float* src = coeffs + ((size_t)i * OUT_DIM + o) * NB;
    float4 v0 = *(const float4*)src;
    float4 v1 = *(const float4*)(src + 4);
    us8 v;
    v[0] = f2bf(v0.x); v[1] = f2bf(v0.y); v[2] = f2bf(v0.z); v[3] = f2bf(v0.w);
    v[4] = f2bf(v1.x); v[5] = f2bf(v1.y); v[6] = f2bf(v1.z); v[7] = f2bf(v1.w);
    *(us8*)(Bt + (size_t)o * KD + i * NB) = v;  // 16B store
}

// ---------------------------------------------------------------------------
// Kernel 3: GEMM  C[M,N] = A[M,KD] * Bt[N,KD]^T   (bf16 -> fp32)
// BM=128 BN=64 BK=32, 256 threads (4 waves, wave grid 2x2, wave tile 64x32)
// grid = 32*16 = 512 blocks -> 2 blocks/CU
// ---------------------------------------------------------------------------
#define BM 128
#define BN 64
#define BK 32

__global__ __launch_bounds__(256, 2) void gemm_kernel(
    const unsigned short* __restrict__ A,    // bf16 bits [BATCH][KD]
    const unsigned short* __restrict__ Bt,   // bf16 bits [OUT_DIM][KD]
    float* __restrict__ C) {                 // [BATCH][OUT_DIM]
    __shared__ __align__(16) unsigned short lA[BM * BK];  // 8 KB, k contiguous
    __shared__ __align__(16) unsigned short lB[BN * BK];  // 4 KB

    const int tid = threadIdx.x;
    const int bn0 = (blockIdx.x & 15) * BN;
    const int bm0 = (blockIdx.x >> 4) * BM;

    const int lane  = tid & 63;
    const int wid   = tid >> 6;
    const int wm    = (wid & 1) * 64;
    const int wn    = (wid >> 1) * 32;
    const int row16 = lane & 15;
    const int quad  = lane >> 4;

    // ds_read offsets (elements). XOR swizzle p = chunk ^ ((row>>1)&3) spreads
    // the 16 rows of a quad over all 8 16B bank-slots (2-way only = free).
    int aOff[4], bOff[2];
#pragma unroll
    for (int mt = 0; mt < 4; ++mt) {
        int r = wm + mt * 16 + row16;
        int p = quad ^ ((r >> 1) & 3);
        aOff[mt] = r * BK + p * 8;
    }
#pragma unroll
    for (int nt = 0; nt < 2; ++nt) {
        int c = wn + nt * 16 + row16;
        int p = quad ^ ((c >> 1) & 3);
        bOff[nt] = c * BK + p * 8;
    }

    // Staging: A tile = 512 x 16B chunks (2/thread), B tile = 256 (1/thread).
    // LDS dest is chunkid*16 (lane-contiguous, required by global_load_lds);
    // the XOR swizzle is applied on the *global* k-chunk instead.
    const int cA1 = tid + 256;
    const int rA0 = tid >> 2, pA0 = tid & 3;
    const int rA1 = cA1 >> 2, pA1 = cA1 & 3;
    const int rB  = tid >> 2, pB  = tid & 3;
    const unsigned short* gA0 = A  + (size_t)(bm0 + rA0) * KD + (pA0 ^ ((rA0 >> 1) & 3)) * 8;
    const unsigned short* gA1 = A  + (size_t)(bm0 + rA1) * KD + (pA1 ^ ((rA1 >> 1) & 3)) * 8;
    const unsigned short* gB  = Bt + (size_t)(bn0 + rB ) * KD + (pB  ^ ((rB  >> 1) & 3)) * 8;
    unsigned short* dA0 = lA + tid * 8;
    unsigned short* dA1 = lA + cA1 * 8;
    unsigned short* dB  = lB + tid * 8;

    f32x4 acc[4][2] = {};

    for (int k0 = 0; k0 < KD; k0 += BK) {
        ld_lds16(gA0 + k0, dA0);
        ld_lds16(gA1 + k0, dA1);
        ld_lds16(gB  + k0, dB);
        __syncthreads();

        bf16x8 aF[4], bF[2];
#pragma unroll
        for (int mt = 0; mt < 4; ++mt) aF[mt] = *(const bf16x8*)(lA + aOff[mt]);
#pragma unroll
        for (int nt = 0; nt < 2; ++nt) bF[nt] = *(const bf16x8*)(lB + bOff[nt]);
#pragma unroll
        for (int mt = 0; mt < 4; ++mt)
#pragma unroll
            for (int nt = 0; nt < 2; ++nt)
                acc[mt][nt] = __builtin_amdgcn_mfma_f32_16x16x32_bf16(
                    aF[mt], bF[nt], acc[mt][nt], 0, 0, 0);
        __syncthreads();
    }

    // C/D layout (m89-verified): col = lane&15, row = quad*4 + reg
#pragma unroll
    for (int mt = 0; mt < 4; ++mt) {
        const int rbase = bm0 + wm + mt * 16 + quad * 4;
#pragma unroll
        for (int nt = 0; nt < 2; ++nt) {
            const int col = bn0 + wn + nt * 16 + row16;
#pragma unroll
            for (int r = 0; r < 4; ++r)
                C[(size_t)(rbase + r) * OUT_DIM + col] = acc[mt][nt][r];
        }
    }
}

// ---------------------------------------------------------------------------
// Fallback (only if ws too small): fp32, block per batch row, basis in LDS.
// ---------------------------------------------------------------------------
__global__ __launch_bounds__(256) void fallback_kernel(
    const float* __restrict__ x, const float* __restrict__ ap,
    const float* __restrict__ qp, const float* __restrict__ coeffs,
    float* __restrict__ out) {
    __shared__ float sb[IN_DIM][NB];   // 32 KB
    const int b = blockIdx.x;
    const float a = ap[0], q = qp[0];
    for (int i = threadIdx.x; i < IN_DIM; i += 256) {
        float xt = tanhf(x[(size_t)b * IN_DIM + i]);
        float p0 = 1.0f, p1 = xt - a;
        sb[i][0] = p0; sb[i][1] = p1;
        float qn = q, qn1 = 1.0f;
#pragma unroll
        for (int n = 2; n < NB; ++n) {
            qn *= q; qn1 *= q;
            float p2 = (xt - (a + qn)) * p1 - a * qn1 * p0;
            sb[i][n] = p2;
            p0 = p1; p1 = p2;
        }
    }
    __syncthreads();
    float acc[4] = {0.f, 0.f, 0.f, 0.f};
    for (int i = 0; i < IN_DIM; ++i) {
        float bb[NB];
#pragma unroll
        for (int d = 0; d < NB; ++d) bb[d] = sb[i][d];
#pragma unroll
        for (int j = 0; j < 4; ++j) {
            int o = threadIdx.x + j * 256;
            const float* cf = coeffs + ((size_t)i * OUT_DIM + o) * NB;
            float s = 0.f;
#pragma unroll
            for (int d = 0; d < NB; ++d) s += bb[d] * cf[d];
            acc[j] += s;
        }
    }
#pragma unroll
    for (int j = 0; j < 4; ++j)
        out[(size_t)b * OUT_DIM + threadIdx.x + j * 256] = acc[j];
}

// ---------------------------------------------------------------------------
extern "C" void kernel_launch(void* const* d_in, const int* in_sizes, int n_in,
                              void* d_out, int out_size, void* d_ws, size_t ws_size,
                              hipStream_t stream) {
    const float* x      = (const float*)d_in[0];
    const float* a      = (const float*)d_in[1];
    const float* q      = (const float*)d_in[2];
    const float* coeffs = (const float*)d_in[3];
    float* out = (float*)d_out;

    const size_t needA = (size_t)BATCH * KD * sizeof(unsigned short);   // 64 MB
    const size_t needB = (size_t)OUT_DIM * KD * sizeof(unsigned short); // 16 MB

    if (ws_size >= needA + needB) {
        unsigned short* Aw = (unsigned short*)d_ws;
        unsigned short* Bt = Aw + (size_t)BATCH * KD;
        prep_basis<<<BATCH * IN_DIM / 256, 256, 0, stream>>>(x, a, q, Aw);
        repack_coeffs<<<OUT_DIM * IN_DIM / 256, 256, 0, stream>>>(coeffs, Bt);
        gemm_kernel<<<(BATCH / BM) * (OUT_DIM / BN), 256, 0, stream>>>(Aw, Bt, out);
    } else {
        fallback_kernel<<<BATCH, 256, 0, stream>>>(x, a, q, coeffs, out);
    }
}

// Round 2
// 217.676 us; speedup vs baseline: 1.0817x; 1.0817x over previous
//
#include <hip/hip_runtime.h>

#define BATCH   4096
#define IN_DIM  1024
#define OUT_DIM 1024
#define NB      8                 // DEGREE + 1
#define KD      (IN_DIM * NB)     // 8192

typedef __bf16 bf16x8 __attribute__((ext_vector_type(8)));
typedef float  f32x4  __attribute__((ext_vector_type(4)));
typedef unsigned short us8 __attribute__((ext_vector_type(8)));

__device__ __forceinline__ unsigned short f2bf(float f) {
    unsigned int u = __float_as_uint(f);
    u += 0x7fffu + ((u >> 16) & 1u);   // round-to-nearest-even
    return (unsigned short)(u >> 16);
}

__device__ __forceinline__ void ld_lds16(const unsigned short* g, unsigned short* l) {
    __builtin_amdgcn_global_load_lds(
        (const __attribute__((address_space(1))) void*)g,
        (__attribute__((address_space(3))) void*)l, 16, 0, 0);
}

// ---------------------------------------------------------------------------
// Kernel 1: basis prep. A[b*KD + i*8 + d] = bf16(P_d(tanh(x[b,i])))
// ---------------------------------------------------------------------------
__global__ __launch_bounds__(256) void prep_basis(
    const float* __restrict__ x, const float* __restrict__ ap,
    const float* __restrict__ qp, unsigned short* __restrict__ Aw) {
    int idx = blockIdx.x * 256 + threadIdx.x;   // (b, i) flat, exact grid
    float a = ap[0], q = qp[0];
    float xt = tanhf(x[idx]);
    float p[NB];
    p[0] = 1.0f;
    p[1] = xt - a;
    float qn = q, qn1 = 1.0f;   // q^n, q^(n-1)
#pragma unroll
    for (int n = 2; n < NB; ++n) {
        qn *= q; qn1 *= q;
        p[n] = (xt - (a + qn)) * p[n - 1] - a * qn1 * p[n - 2];
    }
    us8 v;
#pragma unroll
    for (int d = 0; d < NB; ++d) v[d] = f2bf(p[d]);
    *(us8*)(Aw + (size_t)idx * NB) = v;   // 16B coalesced store
}

// ---------------------------------------------------------------------------
// Kernel 2: coeffs [I][O][8] fp32 -> Bt [O][KD] bf16 via LDS tile transpose.
// Block patch: TI=32 i-rows x TO=64 o-cols. Reads: 64 consecutive o = 2 KB
// contiguous. Writes: 32 consecutive 16B chunks = 512 B contiguous per o-row.
// LDS 16B chunks XOR-swizzled by (o & 31) to break the 512 B row stride.
// ---------------------------------------------------------------------------
#define TI 32
#define TO 64

__global__ __launch_bounds__(256) void repack_coeffs(
    const float* __restrict__ coeffs, unsigned short* __restrict__ Bt) {
    __shared__ __align__(16) unsigned short lt[TO * TI * NB];  // 32 KB
    const int tid = threadIdx.x;
    const int i0 = (blockIdx.x & 31) * TI;
    const int o0 = (blockIdx.x >> 5) * TO;

    // read phase: i_local = pass*4 + tid/64, o_local = tid&63
    {
        const int o_local = tid & 63;
        const int swz = o_local & 31;
#pragma unroll
        for (int pass = 0; pass < 8; ++pass) {
            const int i_local = pass * 4 + (tid >> 6);
            const float* src = coeffs +
                ((size_t)(i0 + i_local) * OUT_DIM + (o0 + o_local)) * NB;
            float4 v0 = *(const float4*)src;
            float4 v1 = *(const float4*)(src + 4);
            us8 v;
            v[0] = f2bf(v0.x); v[1] = f2bf(v0.y); v[2] = f2bf(v0.z); v[3] = f2bf(v0.w);
            v[4] = f2bf(v1.x); v[5] = f2bf(v1.y); v[6] = f2bf(v1.z); v[7] = f2bf(v1.w);
            *(us8*)(lt + o_local * (TI * NB) + (i_local ^ swz) * NB) = v;
        }
    }
    __syncthreads();
    // write phase: o_local = pass*8 + tid/32, chunk c = tid&31
    {
        const int c = tid & 31;
#pragma unroll
        for (int pass = 0; pass < 8; ++pass) {
            const int o_local = pass * 8 + (tid >> 5);
            us8 v = *(const us8*)(lt + o_local * (TI * NB) + (c ^ (o_local & 31)) * NB);
            *(us8*)(Bt + (size_t)(o0 + o_local) * KD + (i0 + c) * NB) = v;
        }
    }
}

// ---------------------------------------------------------------------------
// Kernel 3: GEMM  C[M,N] += A[M,KD] * Bt[N,KD]^T   (bf16 -> fp32, split-K x2)
// BM=BN=128 BK=32, 256 threads (4 waves, wave grid 2x2, wave tile 64x64,
// 16 MFMA : 8 ds_read_b128 per wave-iter). Grid 512 -> 2 blocks/CU.
// Epilogue: fp32 atomicAdd into zeroed C (2 addends -> deterministic).
// ---------------------------------------------------------------------------
#define BM 128
#define BN 128
#define BK 32
#define KSPLIT 2
#define KCH (KD / KSPLIT)   // 4096

__global__ __launch_bounds__(256, 2) void gemm_kernel(
    const unsigned short* __restrict__ A,    // bf16 bits [BATCH][KD]
    const unsigned short* __restrict__ Bt,   // bf16 bits [OUT_DIM][KD]
    float* __restrict__ C) {                 // [BATCH][OUT_DIM], pre-zeroed
    __shared__ __align__(16) unsigned short lA[BM * BK];  // 8 KB
    __shared__ __align__(16) unsigned short lB[BN * BK];  // 8 KB

    const int tid = threadIdx.x;
    const int bidx = blockIdx.x;
    const size_t kbase = (size_t)(bidx >> 8) * KCH;
    const int bn0 = ((bidx & 255) & 7) * BN;
    const int bm0 = ((bidx & 255) >> 3) * BM;

    const int lane  = tid & 63;
    const int wid   = tid >> 6;
    const int wm    = (wid & 1) * 64;
    const int wn    = (wid >> 1) * 64;
    const int row16 = lane & 15;
    const int quad  = lane >> 4;

    // ds_read offsets (elements); XOR swizzle p = quad ^ ((row>>1)&3)
    int aOff[4], bOff[4];
#pragma unroll
    for (int mt = 0; mt < 4; ++mt) {
        int r = wm + mt * 16 + row16;
        aOff[mt] = r * BK + (quad ^ ((r >> 1) & 3)) * 8;
    }
#pragma unroll
    for (int nt = 0; nt < 4; ++nt) {
        int c = wn + nt * 16 + row16;
        bOff[nt] = c * BK + (quad ^ ((c >> 1) & 3)) * 8;
    }

    // Staging: each tile = 512 x 16B chunks; thread handles chunks tid, tid+256
    // for both A and B. LDS dest lane-contiguous; swizzle applied on global k.
    const int r0 = tid >> 2, p0 = tid & 3;
    const int r1 = r0 + 64;
    const unsigned short* gA0 = A + (size_t)(bm0 + r0) * KD + kbase + ((p0 ^ ((r0 >> 1) & 3)) * 8);
    const unsigned short* gA1 = A + (size_t)(bm0 + r1) * KD + kbase + ((p0 ^ ((r1 >> 1) & 3)) * 8);
    const unsigned short* gB0 = Bt + (size_t)(bn0 + r0) * KD + kbase + ((p0 ^ ((r0 >> 1) & 3)) * 8);
    const unsigned short* gB1 = Bt + (size_t)(bn0 + r1) * KD + kbase + ((p0 ^ ((r1 >> 1) & 3)) * 8);
    unsigned short* dA0 = lA + tid * 8;
    unsigned short* dA1 = lA + (tid + 256) * 8;
    unsigned short* dB0 = lB + tid * 8;
    unsigned short* dB1 = lB + (tid + 256) * 8;

    f32x4 acc[4][4] = {};

    for (int k0 = 0; k0 < KCH; k0 += BK) {
        ld_lds16(gA0 + k0, dA0);
        ld_lds16(gA1 + k0, dA1);
        ld_lds16(gB0 + k0, dB0);
        ld_lds16(gB1 + k0, dB1);
        __syncthreads();

        bf16x8 aF[4], bF[4];
#pragma unroll
        for (int mt = 0; mt < 4; ++mt) aF[mt] = *(const bf16x8*)(lA + aOff[mt]);
#pragma unroll
        for (int nt = 0; nt < 4; ++nt) bF[nt] = *(const bf16x8*)(lB + bOff[nt]);
#pragma unroll
        for (int mt = 0; mt < 4; ++mt)
#pragma unroll
            for (int nt = 0; nt < 4; ++nt)
                acc[mt][nt] = __builtin_amdgcn_mfma_f32_16x16x32_bf16(
                    aF[mt], bF[nt], acc[mt][nt], 0, 0, 0);
        __syncthreads();
    }

    // C/D layout (m89-verified): col = lane&15, row = quad*4 + reg
#pragma unroll
    for (int mt = 0; mt < 4; ++mt) {
        const int rbase = bm0 + wm + mt * 16 + quad * 4;
#pragma unroll
        for (int nt = 0; nt < 4; ++nt) {
            const int col = bn0 + wn + nt * 16 + row16;
#pragma unroll
            for (int r = 0; r < 4; ++r)
                atomicAdd(&C[(size_t)(rbase + r) * OUT_DIM + col], acc[mt][nt][r]);
        }
    }
}

// ---------------------------------------------------------------------------
// Fallback (only if ws too small): fp32, block per batch row, basis in LDS.
// ---------------------------------------------------------------------------
__global__ __launch_bounds__(256) void fallback_kernel(
    const float* __restrict__ x, const float* __restrict__ ap,
    const float* __restrict__ qp, const float* __restrict__ coeffs,
    float* __restrict__ out) {
    __shared__ float sb[IN_DIM][NB];   // 32 KB
    const int b = blockIdx.x;
    const float a = ap[0], q = qp[0];
    for (int i = threadIdx.x; i < IN_DIM; i += 256) {
        float xt = tanhf(x[(size_t)b * IN_DIM + i]);
        float p0 = 1.0f, p1 = xt - a;
        sb[i][0] = p0; sb[i][1] = p1;
        float qn = q, qn1 = 1.0f;
#pragma unroll
        for (int n = 2; n < NB; ++n) {
            qn *= q; qn1 *= q;
            float p2 = (xt - (a + qn)) * p1 - a * qn1 * p0;
            sb[i][n] = p2;
            p0 = p1; p1 = p2;
        }
    }
    __syncthreads();
    float acc[4] = {0.f, 0.f, 0.f, 0.f};
    for (int i = 0; i < IN_DIM; ++i) {
        float bb[NB];
#pragma unroll
        for (int d = 0; d < NB; ++d) bb[d] = sb[i][d];
#pragma unroll
        for (int j = 0; j < 4; ++j) {
            int o = threadIdx.x + j * 256;
            const float* cf = coeffs + ((size_t)i * OUT_DIM + o) * NB;
            float s = 0.f;
#pragma unroll
            for (int d = 0; d < NB; ++d) s += bb[d] * cf[d];
            acc[j] += s;
        }
    }
#pragma unroll
    for (int j = 0; j < 4; ++j)
        out[(size_t)b * OUT_DIM + threadIdx.x + j * 256] = acc[j];
}

// ---------------------------------------------------------------------------
extern "C" void kernel_launch(void* const* d_in, const int* in_sizes, int n_in,
                              void* d_out, int out_size, void* d_ws, size_t ws_size,
                              hipStream_t stream) {
    const float* x      = (const float*)d_in[0];
    const float* a      = (const float*)d_in[1];
    const float* q      = (const float*)d_in[2];
    const float* coeffs = (const float*)d_in[3];
    float* out = (float*)d_out;

    const size_t needA = (size_t)BATCH * KD * sizeof(unsigned short);   // 64 MB
    const size_t needB = (size_t)OUT_DIM * KD * sizeof(unsigned short); // 16 MB

    if (ws_size >= needA + needB) {
        unsigned short* Aw = (unsigned short*)d_ws;
        unsigned short* Bt = Aw + (size_t)BATCH * KD;
        prep_basis<<<BATCH * IN_DIM / 256, 256, 0, stream>>>(x, a, q, Aw);
        repack_coeffs<<<(IN_DIM / TI) * (OUT_DIM / TO), 256, 0, stream>>>(coeffs, Bt);
        hipMemsetAsync(out, 0, (size_t)out_size * sizeof(float), stream);
        gemm_kernel<<<(BATCH / BM) * (OUT_DIM / BN) * KSPLIT, 256, 0, stream>>>(Aw, Bt, out);
    } else {
        fallback_kernel<<<BATCH, 256, 0, stream>>>(x, a, q, coeffs, out);
    }
}